// Round 15
// baseline (118.373 us; speedup 1.0000x reference)
//
#include <hip/hip_runtime.h>

// GCN block: delta = segment_sum( (x @ W^T)[source] * ew, target )
//          = segment_sum( x[source] * ew, target ) @ W^T   (linearity)
//
// R15: R14 structure; fat prep rebalanced per R14 counters (29us @2.1TB/s,
// limited by pair-write line amplification + cursor atomics):
//  - SCAT_BLOCKS 256->128: ~5 edges/bucket/block -> 40B runs (ampl 3->1.9x),
//    cursor atomics halved.
//  - CONV_BLOCKS 256->384: balance the two roles (convert ~7us).
// D unchanged: 77.4us = compulsory per-XCD random-line floor (95MB =
// 12.8MB x 8 XCDs at ~1.5TB/s random-line service; proven R7-R13).

#define D     64     // D_IN == D_OUT == 64
#define BKT   64     // nodes per bucket
#define BSH   6      // log2(BKT)
#define NBMAX 2048   // max buckets (scan kernel / LDS hist limit)
#define CAP   1024   // edges per in-LDS sort chunk
#define CAPB  1024   // slack slots per bucket (mean 640, +15 sigma)
#define SCAT_BLOCKS 128
#define CONV_BLOCKS 384

// ---------------- fallback: atomic edge scatter (R1) ----------------
__global__ __launch_bounds__(256) void gcn_scatter_kernel(
    const float* __restrict__ x, const float* __restrict__ ew,
    const int* __restrict__ src, const int* __restrict__ tgt,
    float* __restrict__ s, int n_edges)
{
    int lane = threadIdx.x & 63;
    int e = blockIdx.x * 4 + (threadIdx.x >> 6);
    if (e >= n_edges) return;
    int sn = src[e];
    int tn = tgt[e];
    float w = ew[e];
    float v = x[(size_t)sn * D + lane] * w;
    atomicAdd(&s[(size_t)tn * D + lane], v);
}

// ---------------- fallback: out = s @ W^T (R1) ----------------
__global__ __launch_bounds__(256) void gcn_gemm_kernel(
    const float* __restrict__ s, const float* __restrict__ W,
    float* __restrict__ out, int n_nodes)
{
    __shared__ float4 xs[64 * 17];
    const int tid  = threadIdx.x;
    const int lane = tid & 63;
    const int wid  = __builtin_amdgcn_readfirstlane(tid >> 6);
    const int row0 = blockIdx.x * 64;

    const float4* s4 = reinterpret_cast<const float4*>(s);
#pragma unroll
    for (int k = 0; k < 4; ++k) {
        int f  = tid + k * 256;
        int r  = f >> 4;
        int c4 = f & 15;
        float4 v = make_float4(0.f, 0.f, 0.f, 0.f);
        if (row0 + r < n_nodes)
            v = s4[(size_t)(row0 + r) * 16 + c4];
        xs[r * 17 + c4] = v;
    }
    __syncthreads();

    float acc[16];
#pragma unroll
    for (int j = 0; j < 16; ++j) acc[j] = 0.f;

    const int o0 = wid * 16;
    const float4* W4 = reinterpret_cast<const float4*>(W);
#pragma unroll
    for (int d4 = 0; d4 < 16; ++d4) {
        float4 xv = xs[lane * 17 + d4];
#pragma unroll
        for (int j = 0; j < 16; ++j) {
            float4 wv = W4[(size_t)(o0 + j) * 16 + d4];
            acc[j] += xv.x * wv.x + xv.y * wv.y + xv.z * wv.z + xv.w * wv.w;
        }
    }

    const int row = row0 + lane;
    if (row < n_nodes) {
        float4* out4 = reinterpret_cast<float4*>(out);
#pragma unroll
        for (int j4 = 0; j4 < 4; ++j4) {
            float4 v = make_float4(acc[j4 * 4 + 0], acc[j4 * 4 + 1],
                                   acc[j4 * 4 + 2], acc[j4 * 4 + 3]);
            out4[(size_t)row * 16 + wid * 4 + j4] = v;
        }
    }
}

__device__ __forceinline__ unsigned f2bf(float f) {
    unsigned u = __float_as_uint(f);
    return (u + 0x7FFFu + ((u >> 16) & 1u)) >> 16;   // RNE; inputs finite
}

// ---------------- FAT (slack): convert x->bf16 || scatter pairs ----------
__global__ __launch_bounds__(256) void fat_prep_kernel(
    const float* __restrict__ x, uint2* __restrict__ xb, int n4,
    const int* __restrict__ src, const int* __restrict__ tgt,
    const float* __restrict__ ew, int* __restrict__ bcnt,
    int2* __restrict__ pairs, int n_edges, int nb, int epb)
{
    const int tid = threadIdx.x;

    if (blockIdx.x >= SCAT_BLOCKS) {
        // ---- convert role ----
        const int cb = blockIdx.x - SCAT_BLOCKS;
        const float4* x4 = reinterpret_cast<const float4*>(x);
        for (int i = cb * 256 + tid; i < n4; i += CONV_BLOCKS * 256) {
            float4 v = x4[i];
            uint2 o;
            o.x = f2bf(v.x) | (f2bf(v.y) << 16);
            o.y = f2bf(v.z) | (f2bf(v.w) << 16);
            xb[i] = o;
        }
        return;
    }

    // ---- scatter role ----
    __shared__ int h[NBMAX];        // counts, then rank counters
    __shared__ int base[NBMAX];
    for (int i = tid; i < nb; i += 256) h[i] = 0;
    __syncthreads();
    const int e0 = blockIdx.x * epb;
    const int e1 = min(e0 + epb, n_edges);

    for (int e = e0 + tid; e < e1; e += 256)
        atomicAdd(&h[tgt[e] >> BSH], 1);
    __syncthreads();

    for (int b = tid; b < nb; b += 256) {
        int c = h[b];
        base[b] = c ? (b * CAPB + atomicAdd(&bcnt[b], c)) : 0;
        h[b] = 0;                   // reuse as rank counter
    }
    __syncthreads();

    for (int e = e0 + tid; e < e1; e += 256) {
        int t = tgt[e];
        int b = t >> BSH;
        int r = atomicAdd(&h[b], 1);
        pairs[base[b] + r] =
            make_int2(((t & (BKT - 1)) << 24) | src[e], __float_as_int(ew[e]));
    }
}

// ---------------- A (exact): convert + bucket histogram ----------------
__global__ __launch_bounds__(256) void convert_hist_kernel(
    const float* __restrict__ x, uint2* __restrict__ xb, int n4,
    const int* __restrict__ tgt, int* __restrict__ bcnt,
    int n_edges, int nb, int epb)
{
    __shared__ int h[NBMAX];
    const int tid = threadIdx.x;
    for (int i = tid; i < nb; i += 256) h[i] = 0;

    const float4* x4 = reinterpret_cast<const float4*>(x);
    for (int i = blockIdx.x * 256 + tid; i < n4; i += gridDim.x * 256) {
        float4 v = x4[i];
        uint2 o;
        o.x = f2bf(v.x) | (f2bf(v.y) << 16);
        o.y = f2bf(v.z) | (f2bf(v.w) << 16);
        xb[i] = o;
    }
    __syncthreads();

    const int e0 = blockIdx.x * epb;
    const int e1 = min(e0 + epb, n_edges);
    for (int e = e0 + tid; e < e1; e += 256)
        atomicAdd(&h[tgt[e] >> BSH], 1);
    __syncthreads();
    for (int b = tid; b < nb; b += 256) {
        int c = h[b];
        if (c) atomicAdd(&bcnt[b], c);
    }
}

// ---------------- B (exact): exclusive scan of bucket counts ----------
__global__ __launch_bounds__(1024) void bucket_scan_kernel(
    const int* __restrict__ bcnt, int* __restrict__ bstarts,
    int* __restrict__ bcur, int nb, int n_edges)
{
    __shared__ int lds[1024];
    const int tid = threadIdx.x;
    const int i0 = 2 * tid, i1 = 2 * tid + 1;
    int v0 = (i0 < nb) ? bcnt[i0] : 0;
    int v1 = (i1 < nb) ? bcnt[i1] : 0;
    int tsum = v0 + v1;
    lds[tid] = tsum;
    __syncthreads();
    for (int off = 1; off < 1024; off <<= 1) {
        int a = (tid >= off) ? lds[tid - off] : 0;
        __syncthreads();
        lds[tid] += a;
        __syncthreads();
    }
    int pre = lds[tid] - tsum;     // exclusive
    if (i0 < nb) { bstarts[i0] = pre;      bcur[i0] = pre; }
    if (i1 < nb) { bstarts[i1] = pre + v0; bcur[i1] = pre + v0; }
    if (tid == 0) bstarts[nb] = n_edges;   // sentinel so bend = bstarts+1
}

// ---------------- C (exact): scatter edges into bucket runs ----------
__global__ __launch_bounds__(256) void bucket_scatter_kernel(
    const int* __restrict__ src, const int* __restrict__ tgt,
    const float* __restrict__ ew, int* __restrict__ bcur,
    int2* __restrict__ pairs, int n_edges, int nb, int epb)
{
    __shared__ int h[NBMAX];        // counts, then rank counters
    __shared__ int base[NBMAX];
    const int tid = threadIdx.x;
    for (int i = tid; i < nb; i += 256) h[i] = 0;
    __syncthreads();
    const int e0 = blockIdx.x * epb;
    const int e1 = min(e0 + epb, n_edges);

    for (int e = e0 + tid; e < e1; e += 256)
        atomicAdd(&h[tgt[e] >> BSH], 1);
    __syncthreads();

    for (int b = tid; b < nb; b += 256) {
        int c = h[b];
        base[b] = c ? atomicAdd(&bcur[b], c) : 0;
        h[b] = 0;                   // reuse as rank counter
    }
    __syncthreads();

    for (int e = e0 + tid; e < e1; e += 256) {
        int t = tgt[e];
        int b = t >> BSH;
        int r = atomicAdd(&h[b], 1);
        pairs[base[b] + r] =
            make_int2(((t & (BKT - 1)) << 24) | src[e], __float_as_int(ew[e]));
    }
}

// ---------------- D: per-bucket LDS sort + 4-way-interleaved gather + GEMM -
// R12's proven kernel. capb>0: slab mode (beg=b*capb, end=beg+bend[b]);
// capb==0: exact mode (beg=bbeg[b], end=bend[b]).
__global__ __launch_bounds__(512, 6) void bucket_sort_reduce_gemm_kernel(
    const uint2* __restrict__ xb, const float* __restrict__ W,
    const int* __restrict__ bbeg, const int* __restrict__ bend,
    const int2* __restrict__ pairs,
    float* __restrict__ out, int n_nodes, int nb, int capb)
{
    __shared__ float Wl[64 * 66];       // 16.9 KB; W[o][d] at Wl[o*66+d]
    __shared__ int2  ep[CAP];           // 8 KB, node-sorted chunk
    __shared__ int   segIncl[BKT];      // inclusive per-node counts
    __shared__ int   rankc[BKT];        // scatter cursors
    __shared__ float accRow[8][64];     // per-wave row buffer

    const int tid  = threadIdx.x;
    const int lane = tid & 63;
    const int wv   = tid >> 6;          // 0..7
    const int q4   = lane >> 4;         // quarter 0..3
    const int m    = lane & 15;         // feature-quad index

    for (int i = tid; i < 64 * 64; i += 512)
        Wl[(i >> 6) * 66 + (i & 63)] = W[i];

    const int b   = blockIdx.x;
    const int beg = capb ? b * capb : bbeg[b];
    const int end = capb ? beg + bend[b] : bend[b];

    float4 acc[8];
#pragma unroll
    for (int s = 0; s < 8; ++s) acc[s] = make_float4(0.f, 0.f, 0.f, 0.f);

    for (int cbeg = beg; cbeg < end; cbeg += CAP) {
        const int ccnt = min(CAP, end - cbeg);

        // -- load this chunk's pairs into registers (2 per thread) --
        int2 pr0 = make_int2(0, 0), pr1 = make_int2(0, 0);
        if (tid < ccnt)       pr0 = pairs[cbeg + tid];
        if (tid + 512 < ccnt) pr1 = pairs[cbeg + tid + 512];

        if (tid < BKT) segIncl[tid] = 0;
        __syncthreads();

        // -- pass 1: histogram tloc (from regs) --
        if (tid < ccnt)       atomicAdd(&segIncl[((unsigned)pr0.x) >> 24], 1);
        if (tid + 512 < ccnt) atomicAdd(&segIncl[((unsigned)pr1.x) >> 24], 1);
        __syncthreads();

        // -- 64-bin scan by wave 0 (shfl) --
        if (wv == 0) {
            int c0 = segIncl[lane];
            int v = c0;
#pragma unroll
            for (int off = 1; off < 64; off <<= 1) {
                int n = __shfl_up(v, off);
                if (lane >= off) v += n;
            }
            segIncl[lane] = v;          // inclusive
            rankc[lane]   = v - c0;     // exclusive start
        }
        __syncthreads();

        // -- pass 2: scatter into node-sorted LDS (from regs) --
        if (tid < ccnt) {
            int pos = atomicAdd(&rankc[((unsigned)pr0.x) >> 24], 1);
            ep[pos] = pr0;
        }
        if (tid + 512 < ccnt) {
            int pos = atomicAdd(&rankc[((unsigned)pr1.x) >> 24], 1);
            ep[pos] = pr1;
        }
        __syncthreads();

        // -- 4-way interleaved quad-gather: group g covers s = g*4+k --
#pragma unroll
        for (int g = 0; g < 2; ++g) {
            int e0, e1, e2, e3, x1_0, x1_1, x1_2, x1_3;
            {
                const int tl0 = (g * 4 + 0) * 8 + wv;
                const int tl1 = (g * 4 + 1) * 8 + wv;
                const int tl2 = (g * 4 + 2) * 8 + wv;
                const int tl3 = (g * 4 + 3) * 8 + wv;
                e0 = __builtin_amdgcn_readfirstlane(tl0 ? segIncl[tl0 - 1] : 0);
                e1 = __builtin_amdgcn_readfirstlane(segIncl[tl1 - 1]);
                e2 = __builtin_amdgcn_readfirstlane(segIncl[tl2 - 1]);
                e3 = __builtin_amdgcn_readfirstlane(segIncl[tl3 - 1]);
                x1_0 = __builtin_amdgcn_readfirstlane(segIncl[tl0]);
                x1_1 = __builtin_amdgcn_readfirstlane(segIncl[tl1]);
                x1_2 = __builtin_amdgcn_readfirstlane(segIncl[tl2]);
                x1_3 = __builtin_amdgcn_readfirstlane(segIncl[tl3]);
            }
            const int c1_0 = max(x1_0 - 1, 0);
            const int c1_1 = max(x1_1 - 1, 0);
            const int c1_2 = max(x1_2 - 1, 0);
            const int c1_3 = max(x1_3 - 1, 0);
            float4 a0 = acc[g * 4 + 0];
            float4 a1 = acc[g * 4 + 1];
            float4 a2 = acc[g * 4 + 2];
            float4 a3 = acc[g * 4 + 3];

            while ((e0 < x1_0) | (e1 < x1_1) | (e2 < x1_2) | (e3 < x1_3)) {
                const int ea0 = e0 + q4, ea1 = e1 + q4;
                const int ea2 = e2 + q4, ea3 = e3 + q4;
                int2 p0 = ep[min(ea0, c1_0)];
                int2 p1 = ep[min(ea1, c1_1)];
                int2 p2 = ep[min(ea2, c1_2)];
                int2 p3 = ep[min(ea3, c1_3)];
                // 4 independent quad-gathers -> 16 rows in flight
                uint2 r0 = xb[(size_t)(p0.x & 0xFFFFFF) * 16 + m];
                uint2 r1 = xb[(size_t)(p1.x & 0xFFFFFF) * 16 + m];
                uint2 r2 = xb[(size_t)(p2.x & 0xFFFFFF) * 16 + m];
                uint2 r3 = xb[(size_t)(p3.x & 0xFFFFFF) * 16 + m];
                float w0 = (ea0 < x1_0) ? __int_as_float(p0.y) : 0.f;
                float w1 = (ea1 < x1_1) ? __int_as_float(p1.y) : 0.f;
                float w2 = (ea2 < x1_2) ? __int_as_float(p2.y) : 0.f;
                float w3 = (ea3 < x1_3) ? __int_as_float(p3.y) : 0.f;
                a0.x += w0 * __uint_as_float(r0.x << 16);
                a0.y += w0 * __uint_as_float(r0.x & 0xFFFF0000u);
                a0.z += w0 * __uint_as_float(r0.y << 16);
                a0.w += w0 * __uint_as_float(r0.y & 0xFFFF0000u);
                a1.x += w1 * __uint_as_float(r1.x << 16);
                a1.y += w1 * __uint_as_float(r1.x & 0xFFFF0000u);
                a1.z += w1 * __uint_as_float(r1.y << 16);
                a1.w += w1 * __uint_as_float(r1.y & 0xFFFF0000u);
                a2.x += w2 * __uint_as_float(r2.x << 16);
                a2.y += w2 * __uint_as_float(r2.x & 0xFFFF0000u);
                a2.z += w2 * __uint_as_float(r2.y << 16);
                a2.w += w2 * __uint_as_float(r2.y & 0xFFFF0000u);
                a3.x += w3 * __uint_as_float(r3.x << 16);
                a3.y += w3 * __uint_as_float(r3.x & 0xFFFF0000u);
                a3.z += w3 * __uint_as_float(r3.y << 16);
                a3.w += w3 * __uint_as_float(r3.y & 0xFFFF0000u);
                e0 += 4; e1 += 4; e2 += 4; e3 += 4;
            }
            acc[g * 4 + 0] = a0;
            acc[g * 4 + 1] = a1;
            acc[g * 4 + 2] = a2;
            acc[g * 4 + 3] = a3;
        }
        __syncthreads();   // protect ep/segIncl before next chunk
    }

    // -- epilogue: merge quarters, out[node][o] = sum_d row[d]*W[o][d] --
    const int node0 = b * BKT;
#pragma unroll
    for (int s = 0; s < 8; ++s) {
        const int node = node0 + s * 8 + wv;
        if (node < n_nodes) {
            float4 a = acc[s];
            a.x += __shfl_xor(a.x, 16); a.y += __shfl_xor(a.y, 16);
            a.z += __shfl_xor(a.z, 16); a.w += __shfl_xor(a.w, 16);
            a.x += __shfl_xor(a.x, 32); a.y += __shfl_xor(a.y, 32);
            a.z += __shfl_xor(a.z, 32); a.w += __shfl_xor(a.w, 32);
            if (lane < 16)
                *reinterpret_cast<float4*>(&accRow[wv][m * 4]) = a;
            asm volatile("s_waitcnt lgkmcnt(0)" ::: "memory");

            float o = 0.f;
            const float2* a2p = reinterpret_cast<const float2*>(&accRow[wv][0]);
            const float2* w2p = reinterpret_cast<const float2*>(&Wl[lane * 66]);
#pragma unroll
            for (int d2 = 0; d2 < 32; ++d2) {
                float2 aq = a2p[d2];   // broadcast
                float2 wq = w2p[d2];
                o += aq.x * wq.x + aq.y * wq.y;
            }
            out[(size_t)node * D + lane] = o;
            asm volatile("s_waitcnt lgkmcnt(0)" ::: "memory"); // drain before overwrite
        }
    }
}

extern "C" void kernel_launch(void* const* d_in, const int* in_sizes, int n_in,
                              void* d_out, int out_size, void* d_ws, size_t ws_size,
                              hipStream_t stream)
{
    const float* x   = (const float*)d_in[0];
    const float* W   = (const float*)d_in[1];
    const float* ew  = (const float*)d_in[2];
    const int*   src = (const int*)d_in[3];
    const int*   tgt = (const int*)d_in[4];

    const int n_nodes = in_sizes[0] / D;
    const int n_edges = in_sizes[2];
    const int nb = (n_nodes + BKT - 1) / BKT;
    const int epbS = (n_edges + SCAT_BLOCKS - 1) / SCAT_BLOCKS;

    // ---- slack layout: [bcnt nb][pairs nb*CAPB][xb] ----
    {
        int*   bcnt  = (int*)d_ws;
        size_t ints  = ((size_t)nb + 1) & ~(size_t)1;   // 8B align
        int2*  pairs = (int2*)((int*)d_ws + ints);
        uint2* xb    = (uint2*)(pairs + (size_t)nb * CAPB);
        const size_t need = ints * 4 + (size_t)nb * CAPB * 8 +
                            (size_t)n_nodes * 128;

        if (nb <= NBMAX && n_nodes <= (1 << 24) && ws_size >= need) {
            hipMemsetAsync(bcnt, 0, (size_t)nb * sizeof(int), stream);
            fat_prep_kernel<<<SCAT_BLOCKS + CONV_BLOCKS, 256, 0, stream>>>(
                x, xb, n_nodes * 16, src, tgt, ew, bcnt, pairs,
                n_edges, nb, epbS);
            bucket_sort_reduce_gemm_kernel<<<nb, 512, 0, stream>>>(
                xb, W, bcnt, bcnt, pairs, (float*)d_out, n_nodes, nb, CAPB);
            return;
        }
    }

    // ---- exact layout: [bcnt NBMAX][bstarts NBMAX+1][bcur NBMAX][pairs][xb]
    {
        int*   bcnt    = (int*)d_ws;
        int*   bstarts = bcnt + NBMAX;
        int*   bcur    = bstarts + NBMAX + 1;
        size_t ints    = 3 * (size_t)NBMAX + 1;
        ints = (ints + 1) & ~(size_t)1;
        int2*  pairs   = (int2*)((int*)d_ws + ints);
        uint2* xb      = (uint2*)(pairs + n_edges);
        const size_t need = ints * 4 + (size_t)n_edges * 8 +
                            (size_t)n_nodes * 128;

        if (nb <= NBMAX && n_nodes <= (1 << 24) && ws_size >= need) {
            hipMemsetAsync(bcnt, 0, (size_t)nb * sizeof(int), stream);
            const int ablocks = 256;
            const int epbA = (n_edges + ablocks - 1) / ablocks;
            convert_hist_kernel<<<ablocks, 256, 0, stream>>>(
                x, xb, n_nodes * 16, tgt, bcnt, n_edges, nb, epbA);
            bucket_scan_kernel<<<1, 1024, 0, stream>>>(bcnt, bstarts, bcur,
                                                       nb, n_edges);
            bucket_scatter_kernel<<<256, 256, 0, stream>>>(
                src, tgt, ew, bcur, pairs, n_edges, nb,
                (n_edges + 255) / 256);
            bucket_sort_reduce_gemm_kernel<<<nb, 512, 0, stream>>>(
                xb, W, bstarts, bstarts + 1, pairs, (float*)d_out,
                n_nodes, nb, 0);
            return;
        }
    }

    // ---- fallback: R1 atomic path ----
    float* s = (float*)d_ws;
    hipMemsetAsync(s, 0, (size_t)n_nodes * D * sizeof(float), stream);
    gcn_scatter_kernel<<<(n_edges + 3) / 4, 256, 0, stream>>>(x, ew, src, tgt, s, n_edges);
    gcn_gemm_kernel<<<(n_nodes + 63) / 64, 256, 0, stream>>>(s, W, (float*)d_out, n_nodes);
}

// Round 16
// 109.696 us; speedup vs baseline: 1.0791x; 1.0791x over previous
//
#include <hip/hip_runtime.h>

// GCN block: delta = segment_sum( (x @ W^T)[source] * ew, target )
//          = segment_sum( x[source] * ew, target ) @ W^T   (linearity)
//
// R16: REVERT to R14's exact configuration (best: 110.8us).
// R15's SCAT 128/CONV 384 rebalance regressed (+7.6us): halving scatter
// blocks doubled per-block serial edge work; amplification theory wrong.
// Structure: memset(6KB) -> fat_prep (256 scatter blocks || 256 convert
// blocks) -> D (R12's bucket sort + 4-way interleaved bf16 quad-gather +
// fused GEMM epilogue).
// D = 77.4us invariant across 9 structural variants: compulsory per-XCD
// random-line traffic (FETCH 95MB = 12.8MB x 8 XCDs) at ~1.5TB/s fabric
// service rate. This is the decomposition's floor.

#define D     64     // D_IN == D_OUT == 64
#define BKT   64     // nodes per bucket
#define BSH   6      // log2(BKT)
#define NBMAX 2048   // max buckets (scan kernel / LDS hist limit)
#define CAP   1024   // edges per in-LDS sort chunk
#define CAPB  1024   // slack slots per bucket (mean 640, +15 sigma)
#define SCAT_BLOCKS 256
#define CONV_BLOCKS 256

// ---------------- fallback: atomic edge scatter (R1) ----------------
__global__ __launch_bounds__(256) void gcn_scatter_kernel(
    const float* __restrict__ x, const float* __restrict__ ew,
    const int* __restrict__ src, const int* __restrict__ tgt,
    float* __restrict__ s, int n_edges)
{
    int lane = threadIdx.x & 63;
    int e = blockIdx.x * 4 + (threadIdx.x >> 6);
    if (e >= n_edges) return;
    int sn = src[e];
    int tn = tgt[e];
    float w = ew[e];
    float v = x[(size_t)sn * D + lane] * w;
    atomicAdd(&s[(size_t)tn * D + lane], v);
}

// ---------------- fallback: out = s @ W^T (R1) ----------------
__global__ __launch_bounds__(256) void gcn_gemm_kernel(
    const float* __restrict__ s, const float* __restrict__ W,
    float* __restrict__ out, int n_nodes)
{
    __shared__ float4 xs[64 * 17];
    const int tid  = threadIdx.x;
    const int lane = tid & 63;
    const int wid  = __builtin_amdgcn_readfirstlane(tid >> 6);
    const int row0 = blockIdx.x * 64;

    const float4* s4 = reinterpret_cast<const float4*>(s);
#pragma unroll
    for (int k = 0; k < 4; ++k) {
        int f  = tid + k * 256;
        int r  = f >> 4;
        int c4 = f & 15;
        float4 v = make_float4(0.f, 0.f, 0.f, 0.f);
        if (row0 + r < n_nodes)
            v = s4[(size_t)(row0 + r) * 16 + c4];
        xs[r * 17 + c4] = v;
    }
    __syncthreads();

    float acc[16];
#pragma unroll
    for (int j = 0; j < 16; ++j) acc[j] = 0.f;

    const int o0 = wid * 16;
    const float4* W4 = reinterpret_cast<const float4*>(W);
#pragma unroll
    for (int d4 = 0; d4 < 16; ++d4) {
        float4 xv = xs[lane * 17 + d4];
#pragma unroll
        for (int j = 0; j < 16; ++j) {
            float4 wv = W4[(size_t)(o0 + j) * 16 + d4];
            acc[j] += xv.x * wv.x + xv.y * wv.y + xv.z * wv.z + xv.w * wv.w;
        }
    }

    const int row = row0 + lane;
    if (row < n_nodes) {
        float4* out4 = reinterpret_cast<float4*>(out);
#pragma unroll
        for (int j4 = 0; j4 < 4; ++j4) {
            float4 v = make_float4(acc[j4 * 4 + 0], acc[j4 * 4 + 1],
                                   acc[j4 * 4 + 2], acc[j4 * 4 + 3]);
            out4[(size_t)row * 16 + wid * 4 + j4] = v;
        }
    }
}

__device__ __forceinline__ unsigned f2bf(float f) {
    unsigned u = __float_as_uint(f);
    return (u + 0x7FFFu + ((u >> 16) & 1u)) >> 16;   // RNE; inputs finite
}

// ---------------- FAT (slack): convert x->bf16 || scatter pairs ----------
// Blocks [0, SCAT_BLOCKS): bucket scatter with count-based slabs
//   (pos = b*CAPB + atomicAdd(&bcnt[b], c); bcnt pre-zeroed by memset).
// Blocks [SCAT_BLOCKS, SCAT_BLOCKS+CONV_BLOCKS): stream-convert x to xb.
__global__ __launch_bounds__(256) void fat_prep_kernel(
    const float* __restrict__ x, uint2* __restrict__ xb, int n4,
    const int* __restrict__ src, const int* __restrict__ tgt,
    const float* __restrict__ ew, int* __restrict__ bcnt,
    int2* __restrict__ pairs, int n_edges, int nb, int epb)
{
    const int tid = threadIdx.x;

    if (blockIdx.x >= SCAT_BLOCKS) {
        // ---- convert role ----
        const int cb = blockIdx.x - SCAT_BLOCKS;
        const float4* x4 = reinterpret_cast<const float4*>(x);
        for (int i = cb * 256 + tid; i < n4; i += CONV_BLOCKS * 256) {
            float4 v = x4[i];
            uint2 o;
            o.x = f2bf(v.x) | (f2bf(v.y) << 16);
            o.y = f2bf(v.z) | (f2bf(v.w) << 16);
            xb[i] = o;
        }
        return;
    }

    // ---- scatter role ----
    __shared__ int h[NBMAX];        // counts, then rank counters
    __shared__ int base[NBMAX];
    for (int i = tid; i < nb; i += 256) h[i] = 0;
    __syncthreads();
    const int e0 = blockIdx.x * epb;
    const int e1 = min(e0 + epb, n_edges);

    for (int e = e0 + tid; e < e1; e += 256)
        atomicAdd(&h[tgt[e] >> BSH], 1);
    __syncthreads();

    for (int b = tid; b < nb; b += 256) {
        int c = h[b];
        base[b] = c ? (b * CAPB + atomicAdd(&bcnt[b], c)) : 0;
        h[b] = 0;                   // reuse as rank counter
    }
    __syncthreads();

    for (int e = e0 + tid; e < e1; e += 256) {
        int t = tgt[e];
        int b = t >> BSH;
        int r = atomicAdd(&h[b], 1);
        pairs[base[b] + r] =
            make_int2(((t & (BKT - 1)) << 24) | src[e], __float_as_int(ew[e]));
    }
}

// ---------------- A (exact): convert + bucket histogram ----------------
__global__ __launch_bounds__(256) void convert_hist_kernel(
    const float* __restrict__ x, uint2* __restrict__ xb, int n4,
    const int* __restrict__ tgt, int* __restrict__ bcnt,
    int n_edges, int nb, int epb)
{
    __shared__ int h[NBMAX];
    const int tid = threadIdx.x;
    for (int i = tid; i < nb; i += 256) h[i] = 0;

    const float4* x4 = reinterpret_cast<const float4*>(x);
    for (int i = blockIdx.x * 256 + tid; i < n4; i += gridDim.x * 256) {
        float4 v = x4[i];
        uint2 o;
        o.x = f2bf(v.x) | (f2bf(v.y) << 16);
        o.y = f2bf(v.z) | (f2bf(v.w) << 16);
        xb[i] = o;
    }
    __syncthreads();

    const int e0 = blockIdx.x * epb;
    const int e1 = min(e0 + epb, n_edges);
    for (int e = e0 + tid; e < e1; e += 256)
        atomicAdd(&h[tgt[e] >> BSH], 1);
    __syncthreads();
    for (int b = tid; b < nb; b += 256) {
        int c = h[b];
        if (c) atomicAdd(&bcnt[b], c);
    }
}

// ---------------- B (exact): exclusive scan of bucket counts ----------
__global__ __launch_bounds__(1024) void bucket_scan_kernel(
    const int* __restrict__ bcnt, int* __restrict__ bstarts,
    int* __restrict__ bcur, int nb, int n_edges)
{
    __shared__ int lds[1024];
    const int tid = threadIdx.x;
    const int i0 = 2 * tid, i1 = 2 * tid + 1;
    int v0 = (i0 < nb) ? bcnt[i0] : 0;
    int v1 = (i1 < nb) ? bcnt[i1] : 0;
    int tsum = v0 + v1;
    lds[tid] = tsum;
    __syncthreads();
    for (int off = 1; off < 1024; off <<= 1) {
        int a = (tid >= off) ? lds[tid - off] : 0;
        __syncthreads();
        lds[tid] += a;
        __syncthreads();
    }
    int pre = lds[tid] - tsum;     // exclusive
    if (i0 < nb) { bstarts[i0] = pre;      bcur[i0] = pre; }
    if (i1 < nb) { bstarts[i1] = pre + v0; bcur[i1] = pre + v0; }
    if (tid == 0) bstarts[nb] = n_edges;   // sentinel so bend = bstarts+1
}

// ---------------- C (exact): scatter edges into bucket runs ----------
__global__ __launch_bounds__(256) void bucket_scatter_kernel(
    const int* __restrict__ src, const int* __restrict__ tgt,
    const float* __restrict__ ew, int* __restrict__ bcur,
    int2* __restrict__ pairs, int n_edges, int nb, int epb)
{
    __shared__ int h[NBMAX];        // counts, then rank counters
    __shared__ int base[NBMAX];
    const int tid = threadIdx.x;
    for (int i = tid; i < nb; i += 256) h[i] = 0;
    __syncthreads();
    const int e0 = blockIdx.x * epb;
    const int e1 = min(e0 + epb, n_edges);

    for (int e = e0 + tid; e < e1; e += 256)
        atomicAdd(&h[tgt[e] >> BSH], 1);
    __syncthreads();

    for (int b = tid; b < nb; b += 256) {
        int c = h[b];
        base[b] = c ? atomicAdd(&bcur[b], c) : 0;
        h[b] = 0;                   // reuse as rank counter
    }
    __syncthreads();

    for (int e = e0 + tid; e < e1; e += 256) {
        int t = tgt[e];
        int b = t >> BSH;
        int r = atomicAdd(&h[b], 1);
        pairs[base[b] + r] =
            make_int2(((t & (BKT - 1)) << 24) | src[e], __float_as_int(ew[e]));
    }
}

// ---------------- D: per-bucket LDS sort + 4-way-interleaved gather + GEMM -
// R12's proven kernel. capb>0: slab mode (beg=b*capb, end=beg+bend[b]);
// capb==0: exact mode (beg=bbeg[b], end=bend[b]).
__global__ __launch_bounds__(512, 6) void bucket_sort_reduce_gemm_kernel(
    const uint2* __restrict__ xb, const float* __restrict__ W,
    const int* __restrict__ bbeg, const int* __restrict__ bend,
    const int2* __restrict__ pairs,
    float* __restrict__ out, int n_nodes, int nb, int capb)
{
    __shared__ float Wl[64 * 66];       // 16.9 KB; W[o][d] at Wl[o*66+d]
    __shared__ int2  ep[CAP];           // 8 KB, node-sorted chunk
    __shared__ int   segIncl[BKT];      // inclusive per-node counts
    __shared__ int   rankc[BKT];        // scatter cursors
    __shared__ float accRow[8][64];     // per-wave row buffer

    const int tid  = threadIdx.x;
    const int lane = tid & 63;
    const int wv   = tid >> 6;          // 0..7
    const int q4   = lane >> 4;         // quarter 0..3
    const int m    = lane & 15;         // feature-quad index

    for (int i = tid; i < 64 * 64; i += 512)
        Wl[(i >> 6) * 66 + (i & 63)] = W[i];

    const int b   = blockIdx.x;
    const int beg = capb ? b * capb : bbeg[b];
    const int end = capb ? beg + bend[b] : bend[b];

    float4 acc[8];
#pragma unroll
    for (int s = 0; s < 8; ++s) acc[s] = make_float4(0.f, 0.f, 0.f, 0.f);

    for (int cbeg = beg; cbeg < end; cbeg += CAP) {
        const int ccnt = min(CAP, end - cbeg);

        // -- load this chunk's pairs into registers (2 per thread) --
        int2 pr0 = make_int2(0, 0), pr1 = make_int2(0, 0);
        if (tid < ccnt)       pr0 = pairs[cbeg + tid];
        if (tid + 512 < ccnt) pr1 = pairs[cbeg + tid + 512];

        if (tid < BKT) segIncl[tid] = 0;
        __syncthreads();

        // -- pass 1: histogram tloc (from regs) --
        if (tid < ccnt)       atomicAdd(&segIncl[((unsigned)pr0.x) >> 24], 1);
        if (tid + 512 < ccnt) atomicAdd(&segIncl[((unsigned)pr1.x) >> 24], 1);
        __syncthreads();

        // -- 64-bin scan by wave 0 (shfl) --
        if (wv == 0) {
            int c0 = segIncl[lane];
            int v = c0;
#pragma unroll
            for (int off = 1; off < 64; off <<= 1) {
                int n = __shfl_up(v, off);
                if (lane >= off) v += n;
            }
            segIncl[lane] = v;          // inclusive
            rankc[lane]   = v - c0;     // exclusive start
        }
        __syncthreads();

        // -- pass 2: scatter into node-sorted LDS (from regs) --
        if (tid < ccnt) {
            int pos = atomicAdd(&rankc[((unsigned)pr0.x) >> 24], 1);
            ep[pos] = pr0;
        }
        if (tid + 512 < ccnt) {
            int pos = atomicAdd(&rankc[((unsigned)pr1.x) >> 24], 1);
            ep[pos] = pr1;
        }
        __syncthreads();

        // -- 4-way interleaved quad-gather: group g covers s = g*4+k --
#pragma unroll
        for (int g = 0; g < 2; ++g) {
            int e0, e1, e2, e3, x1_0, x1_1, x1_2, x1_3;
            {
                const int tl0 = (g * 4 + 0) * 8 + wv;
                const int tl1 = (g * 4 + 1) * 8 + wv;
                const int tl2 = (g * 4 + 2) * 8 + wv;
                const int tl3 = (g * 4 + 3) * 8 + wv;
                e0 = __builtin_amdgcn_readfirstlane(tl0 ? segIncl[tl0 - 1] : 0);
                e1 = __builtin_amdgcn_readfirstlane(segIncl[tl1 - 1]);
                e2 = __builtin_amdgcn_readfirstlane(segIncl[tl2 - 1]);
                e3 = __builtin_amdgcn_readfirstlane(segIncl[tl3 - 1]);
                x1_0 = __builtin_amdgcn_readfirstlane(segIncl[tl0]);
                x1_1 = __builtin_amdgcn_readfirstlane(segIncl[tl1]);
                x1_2 = __builtin_amdgcn_readfirstlane(segIncl[tl2]);
                x1_3 = __builtin_amdgcn_readfirstlane(segIncl[tl3]);
            }
            const int c1_0 = max(x1_0 - 1, 0);
            const int c1_1 = max(x1_1 - 1, 0);
            const int c1_2 = max(x1_2 - 1, 0);
            const int c1_3 = max(x1_3 - 1, 0);
            float4 a0 = acc[g * 4 + 0];
            float4 a1 = acc[g * 4 + 1];
            float4 a2 = acc[g * 4 + 2];
            float4 a3 = acc[g * 4 + 3];

            while ((e0 < x1_0) | (e1 < x1_1) | (e2 < x1_2) | (e3 < x1_3)) {
                const int ea0 = e0 + q4, ea1 = e1 + q4;
                const int ea2 = e2 + q4, ea3 = e3 + q4;
                int2 p0 = ep[min(ea0, c1_0)];
                int2 p1 = ep[min(ea1, c1_1)];
                int2 p2 = ep[min(ea2, c1_2)];
                int2 p3 = ep[min(ea3, c1_3)];
                // 4 independent quad-gathers -> 16 rows in flight
                uint2 r0 = xb[(size_t)(p0.x & 0xFFFFFF) * 16 + m];
                uint2 r1 = xb[(size_t)(p1.x & 0xFFFFFF) * 16 + m];
                uint2 r2 = xb[(size_t)(p2.x & 0xFFFFFF) * 16 + m];
                uint2 r3 = xb[(size_t)(p3.x & 0xFFFFFF) * 16 + m];
                float w0 = (ea0 < x1_0) ? __int_as_float(p0.y) : 0.f;
                float w1 = (ea1 < x1_1) ? __int_as_float(p1.y) : 0.f;
                float w2 = (ea2 < x1_2) ? __int_as_float(p2.y) : 0.f;
                float w3 = (ea3 < x1_3) ? __int_as_float(p3.y) : 0.f;
                a0.x += w0 * __uint_as_float(r0.x << 16);
                a0.y += w0 * __uint_as_float(r0.x & 0xFFFF0000u);
                a0.z += w0 * __uint_as_float(r0.y << 16);
                a0.w += w0 * __uint_as_float(r0.y & 0xFFFF0000u);
                a1.x += w1 * __uint_as_float(r1.x << 16);
                a1.y += w1 * __uint_as_float(r1.x & 0xFFFF0000u);
                a1.z += w1 * __uint_as_float(r1.y << 16);
                a1.w += w1 * __uint_as_float(r1.y & 0xFFFF0000u);
                a2.x += w2 * __uint_as_float(r2.x << 16);
                a2.y += w2 * __uint_as_float(r2.x & 0xFFFF0000u);
                a2.z += w2 * __uint_as_float(r2.y << 16);
                a2.w += w2 * __uint_as_float(r2.y & 0xFFFF0000u);
                a3.x += w3 * __uint_as_float(r3.x << 16);
                a3.y += w3 * __uint_as_float(r3.x & 0xFFFF0000u);
                a3.z += w3 * __uint_as_float(r3.y << 16);
                a3.w += w3 * __uint_as_float(r3.y & 0xFFFF0000u);
                e0 += 4; e1 += 4; e2 += 4; e3 += 4;
            }
            acc[g * 4 + 0] = a0;
            acc[g * 4 + 1] = a1;
            acc[g * 4 + 2] = a2;
            acc[g * 4 + 3] = a3;
        }
        __syncthreads();   // protect ep/segIncl before next chunk
    }

    // -- epilogue: merge quarters, out[node][o] = sum_d row[d]*W[o][d] --
    const int node0 = b * BKT;
#pragma unroll
    for (int s = 0; s < 8; ++s) {
        const int node = node0 + s * 8 + wv;
        if (node < n_nodes) {
            float4 a = acc[s];
            a.x += __shfl_xor(a.x, 16); a.y += __shfl_xor(a.y, 16);
            a.z += __shfl_xor(a.z, 16); a.w += __shfl_xor(a.w, 16);
            a.x += __shfl_xor(a.x, 32); a.y += __shfl_xor(a.y, 32);
            a.z += __shfl_xor(a.z, 32); a.w += __shfl_xor(a.w, 32);
            if (lane < 16)
                *reinterpret_cast<float4*>(&accRow[wv][m * 4]) = a;
            asm volatile("s_waitcnt lgkmcnt(0)" ::: "memory");

            float o = 0.f;
            const float2* a2p = reinterpret_cast<const float2*>(&accRow[wv][0]);
            const float2* w2p = reinterpret_cast<const float2*>(&Wl[lane * 66]);
#pragma unroll
            for (int d2 = 0; d2 < 32; ++d2) {
                float2 aq = a2p[d2];   // broadcast
                float2 wq = w2p[d2];
                o += aq.x * wq.x + aq.y * wq.y;
            }
            out[(size_t)node * D + lane] = o;
            asm volatile("s_waitcnt lgkmcnt(0)" ::: "memory"); // drain before overwrite
        }
    }
}

extern "C" void kernel_launch(void* const* d_in, const int* in_sizes, int n_in,
                              void* d_out, int out_size, void* d_ws, size_t ws_size,
                              hipStream_t stream)
{
    const float* x   = (const float*)d_in[0];
    const float* W   = (const float*)d_in[1];
    const float* ew  = (const float*)d_in[2];
    const int*   src = (const int*)d_in[3];
    const int*   tgt = (const int*)d_in[4];

    const int n_nodes = in_sizes[0] / D;
    const int n_edges = in_sizes[2];
    const int nb = (n_nodes + BKT - 1) / BKT;
    const int epbS = (n_edges + SCAT_BLOCKS - 1) / SCAT_BLOCKS;

    // ---- slack layout: [bcnt nb][pairs nb*CAPB][xb] ----
    {
        int*   bcnt  = (int*)d_ws;
        size_t ints  = ((size_t)nb + 1) & ~(size_t)1;   // 8B align
        int2*  pairs = (int2*)((int*)d_ws + ints);
        uint2* xb    = (uint2*)(pairs + (size_t)nb * CAPB);
        const size_t need = ints * 4 + (size_t)nb * CAPB * 8 +
                            (size_t)n_nodes * 128;

        if (nb <= NBMAX && n_nodes <= (1 << 24) && ws_size >= need) {
            hipMemsetAsync(bcnt, 0, (size_t)nb * sizeof(int), stream);
            fat_prep_kernel<<<SCAT_BLOCKS + CONV_BLOCKS, 256, 0, stream>>>(
                x, xb, n_nodes * 16, src, tgt, ew, bcnt, pairs,
                n_edges, nb, epbS);
            bucket_sort_reduce_gemm_kernel<<<nb, 512, 0, stream>>>(
                xb, W, bcnt, bcnt, pairs, (float*)d_out, n_nodes, nb, CAPB);
            return;
        }
    }

    // ---- exact layout: [bcnt NBMAX][bstarts NBMAX+1][bcur NBMAX][pairs][xb]
    {
        int*   bcnt    = (int*)d_ws;
        int*   bstarts = bcnt + NBMAX;
        int*   bcur    = bstarts + NBMAX + 1;
        size_t ints    = 3 * (size_t)NBMAX + 1;
        ints = (ints + 1) & ~(size_t)1;
        int2*  pairs   = (int2*)((int*)d_ws + ints);
        uint2* xb      = (uint2*)(pairs + n_edges);
        const size_t need = ints * 4 + (size_t)n_edges * 8 +
                            (size_t)n_nodes * 128;

        if (nb <= NBMAX && n_nodes <= (1 << 24) && ws_size >= need) {
            hipMemsetAsync(bcnt, 0, (size_t)nb * sizeof(int), stream);
            const int ablocks = 256;
            const int epbA = (n_edges + ablocks - 1) / ablocks;
            convert_hist_kernel<<<ablocks, 256, 0, stream>>>(
                x, xb, n_nodes * 16, tgt, bcnt, n_edges, nb, epbA);
            bucket_scan_kernel<<<1, 1024, 0, stream>>>(bcnt, bstarts, bcur,
                                                       nb, n_edges);
            bucket_scatter_kernel<<<256, 256, 0, stream>>>(
                src, tgt, ew, bcur, pairs, n_edges, nb,
                (n_edges + 255) / 256);
            bucket_sort_reduce_gemm_kernel<<<nb, 512, 0, stream>>>(
                xb, W, bstarts, bstarts + 1, pairs, (float*)d_out,
                n_nodes, nb, 0);
            return;
        }
    }

    // ---- fallback: R1 atomic path ----
    float* s = (float*)d_ws;
    hipMemsetAsync(s, 0, (size_t)n_nodes * D * sizeof(float), stream);
    gcn_scatter_kernel<<<(n_edges + 3) / 4, 256, 0, stream>>>(x, ew, src, tgt, s, n_edges);
    gcn_gemm_kernel<<<(n_nodes + 63) / 64, 256, 0, stream>>>(s, W, (float*)d_out, n_nodes);
}